// Round 9
// baseline (743.744 us; speedup 1.0000x reference)
//
#include <hip/hip_runtime.h>
#include <hip/hip_bf16.h>
#include <math.h>

// Problem constants (B=4, S=2048, D=768, H=3072, E=8, K=2, cap_factor=1.5)
#define TOK    8192          // B*S tokens
#define DMODEL 768
#define HDIM   3072
#define NEXP   8
#define CAP    1536          // int((B*S/E)*1.5)
#define NFLAT  (TOK*2)

typedef __attribute__((ext_vector_type(8))) short bf16x8;
typedef __attribute__((ext_vector_type(4))) float f32x4;

static __device__ __forceinline__ unsigned short f2bf(float f) {
  unsigned int u = __float_as_uint(f);
  u += 0x7FFF + ((u >> 16) & 1);          // round-to-nearest-even
  return (unsigned short)(u >> 16);
}

// ---------------- 1. Router: fp64 logits, top-2, renormalized weights ----------------
__global__ __launch_bounds__(256)
void moe_router(const float* __restrict__ x, const float* __restrict__ Wr,
                int* __restrict__ eidx, float* __restrict__ pw)
{
  const int wid = threadIdx.x >> 6, lane = threadIdx.x & 63;
  const int t = blockIdx.x * 4 + wid;
  const float* xr = x + (size_t)t * DMODEL;
  double acc[NEXP];
#pragma unroll
  for (int e = 0; e < NEXP; ++e) acc[e] = 0.0;
  for (int j = 0; j < DMODEL / 64; ++j) {
    const int d = j * 64 + lane;
    const double xv = (double)xr[d];
    const float* wrow = Wr + (size_t)d * NEXP;
#pragma unroll
    for (int e = 0; e < NEXP; ++e) acc[e] += xv * (double)wrow[e];
  }
#pragma unroll
  for (int off = 32; off > 0; off >>= 1) {
#pragma unroll
    for (int e = 0; e < NEXP; ++e) acc[e] += __shfl_xor(acc[e], off, 64);
  }
  if (lane == 0) {
    int e0 = 0;
    for (int e = 1; e < NEXP; ++e) if (acc[e] > acc[e0]) e0 = e;
    int e1 = (e0 == 0) ? 1 : 0;
    for (int e = 0; e < NEXP; ++e) { if (e == e0) continue; if (acc[e] > acc[e1]) e1 = e; }
    const double p0 = 1.0 / (1.0 + exp(acc[e1] - acc[e0]));
    eidx[t * 2 + 0] = e0; eidx[t * 2 + 1] = e1;
    pw[t * 2 + 0] = (float)p0; pw[t * 2 + 1] = (float)(1.0 - p0);
  }
}

// ---------------- 2. Capacity assignment ----------------
__global__ __launch_bounds__(256)
void moe_assign(const int* __restrict__ eidx, int* __restrict__ slotpos,
                int* __restrict__ elist, int* __restrict__ counts)
{
  const int e = blockIdx.x;
  const int tid = threadIdx.x;
  const int base = tid * 64;
  int cnt = 0;
  for (int j = 0; j < 64; ++j) cnt += (eidx[base + j] == e);
  const int lane = tid & 63, wid = tid >> 6;
  int incl = cnt;
  for (int off = 1; off < 64; off <<= 1) {
    int u = __shfl_up(incl, off, 64);
    if (lane >= off) incl += u;
  }
  __shared__ int wsum[4];
  if (lane == 63) wsum[wid] = incl;
  __syncthreads();
  int wbase = 0;
  for (int w = 0; w < wid; ++w) wbase += wsum[w];
  int run = wbase + incl - cnt;
  for (int j = 0; j < 64; ++j) {
    const int n = base + j;
    if (eidx[n] == e) {
      const int pos = run++;
      slotpos[n] = (pos < CAP) ? pos : -1;
      if (pos < CAP) elist[e * CAP + pos] = n >> 1;
    }
  }
  if (tid == 255) {
    int tot = wbase + incl;
    counts[e] = (tot < CAP) ? tot : CAP;
  }
}

// ---------------- 3. Transpose + fp32->bf16 convert (weights) ----------------
__global__ __launch_bounds__(256)
void transpose_bf16(const float* __restrict__ in, unsigned short* __restrict__ out,
                    int R, int C)
{
  __shared__ unsigned short tile[64][65];
  const int e = blockIdx.z;
  in  += (size_t)e * R * C;
  out += (size_t)e * C * R;
  const int c0 = blockIdx.x * 64;
  const int r0 = blockIdx.y * 64;
  const int tid = threadIdx.x;
#pragma unroll
  for (int i = 0; i < 16; ++i) {
    const int L = tid + i * 256;
    const int r = L >> 6, c = L & 63;
    tile[r][c] = f2bf(in[(size_t)(r0 + r) * C + c0 + c]);
  }
  __syncthreads();
#pragma unroll
  for (int i = 0; i < 16; ++i) {
    const int L = tid + i * 256;
    const int rr = L & 63, cc = L >> 6;
    out[(size_t)(c0 + cc) * R + r0 + rr] = tile[rr][cc];
  }
}

// ---------------- 4. Gather tokens per expert into contiguous bf16 rows ----------------
__global__ __launch_bounds__(64)
void moe_gather(const float* __restrict__ x, const int* __restrict__ elist,
                const int* __restrict__ counts, unsigned short* __restrict__ Xg)
{
  const int p = blockIdx.x, e = blockIdx.y;
  const int lane = threadIdx.x;
  unsigned short* dst = Xg + ((size_t)e * CAP + p) * DMODEL;
  if (p >= counts[e]) {
    ushort4 z; z.x = z.y = z.z = z.w = 0;
#pragma unroll
    for (int j = 0; j < 3; ++j) ((ushort4*)dst)[j * 64 + lane] = z;
    return;
  }
  const int tok = elist[e * CAP + p];
  const float4* src = (const float4*)(x + (size_t)tok * DMODEL);
#pragma unroll
  for (int j = 0; j < 3; ++j) {
    float4 v = src[j * 64 + lane];
    ushort4 o;
    o.x = f2bf(v.x); o.y = f2bf(v.y); o.z = f2bf(v.z); o.w = f2bf(v.w);
    ((ushort4*)dst)[j * 64 + lane] = o;
  }
}

// ---------------- 5. Grouped GEMM: reg-staged pipeline, fragment-linear LDS ----------------
// 128x128 tile, 256 thr = 4 waves (2x2), wave out 64x64, acc[4][4].
// Transport = global_load_dwordx4 -> regs -> ds_write_b128 (NO global_load_lds:
// its vmcnt(0)-in-sync drain is the component common to all 148-170us variants,
// r7 audit 3290 cyc/block-K-step vs <=600 visible). Loads for tile t+1 issue
// BEFORE compute(t) so HBM/L2 latency hides under MFMA.
// LDS layout = fragment-linear (r3-r7: 0 conflicts measured, absmax-verified):
// block fbl (kh*8+fb) holds rows fb*16..fb*16+15 x k-chunk kh, 1KB contiguous;
// ds_write at fbl*512 + lane*8 is a per-wave bank sweep (conflict-free);
// ds_read_b128 of 1024B/wave mirrors it.
// EPI=0: bf16(gelu(acc+bias)) via LDS-staged coalesced 16B stores (r7: direct
// scalar bf16 stores cost +87% write amplification, 141MB vs 75.5MB).
// EPI=1: direct f32 (clean, r5), bias folded into combine; ks picks Cout0/1.
template <int EPI>
__global__ __launch_bounds__(256, 3)
void moe_rs(const unsigned short* __restrict__ Ag, int lda,
            const unsigned short* __restrict__ Bg, int ldb,
            void* __restrict__ Cout0, void* __restrict__ Cout1, int ldc,
            const float* __restrict__ bias,
            int Nsize, int NT, int MT, int NTN)
{
  __shared__ __align__(16) unsigned short lds[2 * 8192];   // A | B, 32 KiB

  // XCD swizzle: per-XCD contiguous chunk = one expert's tiles; mt fastest
  const int cpx = gridDim.x >> 3;
  const int swz = (blockIdx.x & 7) * cpx + (blockIdx.x >> 3);
  const int e  = swz / cpx;
  int rd = swz - e * cpx;
  const int mt = rd % MT;  rd /= MT;
  const int nt = rd % NTN;
  const int ks = rd / NTN;                   // K-split slice (0 unless GEMM2)
  const int m0 = mt * 128, n0 = nt * 128;
  const int kb = ks * NT * 64;

  const unsigned short* Ae = Ag + (size_t)e * CAP * lda;
  const unsigned short* Be = Bg + (size_t)e * Nsize * ldb;

  const int tid = threadIdx.x, lane = tid & 63, wid = tid >> 6;
  const int wr = wid >> 1, wc = wid & 1;
  const int r16 = lane & 15, g4 = lane >> 4;

  // staging: thread covers fragment blocks fbl = wid*4+j; global source is
  // fragment-ordered: row = (fbl&7)*16 + r16, k-chunk = (fbl>>3)*32 + g4*8.
  // 32-bit offsets (8 VGPR) keep us under the (256,3) 168-VGPR budget.
  int offA[4], offB[4];
#pragma unroll
  for (int j = 0; j < 4; ++j) {
    const int fbl = wid * 4 + j;
    const int row = (fbl & 7) * 16 + r16;
    const int kc  = (fbl >> 3) * 32 + g4 * 8 + kb;
    offA[j] = (m0 + row) * lda + kc;
    offB[j] = (n0 + row) * ldb + kc;
  }

  float4 ra[4], rb[4];
#define LOADT(tt) do {                                                        \
    const int ko = (tt) * 64;                                                 \
    _Pragma("unroll")                                                         \
    for (int j = 0; j < 4; ++j) {                                             \
      ra[j] = *(const float4*)(Ae + offA[j] + ko);                            \
      rb[j] = *(const float4*)(Be + offB[j] + ko);                            \
    }                                                                         \
  } while (0)
#define STORET() do {                                                         \
    _Pragma("unroll")                                                         \
    for (int j = 0; j < 4; ++j) {                                             \
      const int fbl = wid * 4 + j;                                            \
      *(float4*)&lds[fbl * 512 + lane * 8]        = ra[j];                    \
      *(float4*)&lds[8192 + fbl * 512 + lane * 8] = rb[j];                    \
    }                                                                         \
  } while (0)

  f32x4 acc[4][4];
#pragma unroll
  for (int i = 0; i < 4; ++i)
#pragma unroll
    for (int j = 0; j < 4; ++j) acc[i][j] = (f32x4){0.f, 0.f, 0.f, 0.f};

  LOADT(0);
  for (int t = 0; t < NT; ++t) {
    __syncthreads();                 // all waves done reading LDS(t-1)
    STORET();                        // compiler waits vmcnt for ra/rb here
    if (t + 1 < NT) LOADT(t + 1);    // in flight during compute(t)
    __syncthreads();                 // LDS(t) visible
#pragma unroll
    for (int kh = 0; kh < 2; ++kh) {
      bf16x8 aF[4], bF[4];
#pragma unroll
      for (int mi = 0; mi < 4; ++mi)
        aF[mi] = *(const bf16x8*)&lds[(kh * 8 + wr * 4 + mi) * 512 + lane * 8];
#pragma unroll
      for (int ni = 0; ni < 4; ++ni)
        bF[ni] = *(const bf16x8*)&lds[8192 + (kh * 8 + wc * 4 + ni) * 512 + lane * 8];
#pragma unroll
      for (int mi = 0; mi < 4; ++mi)
#pragma unroll
        for (int ni = 0; ni < 4; ++ni)
          acc[mi][ni] = __builtin_amdgcn_mfma_f32_16x16x32_bf16(aF[mi], bF[ni], acc[mi][ni], 0, 0, 0);
    }
  }
#undef LOADT
#undef STORET

  // ---- epilogue. C/D layout: col = lane&15, row = 4*(lane>>4)+reg ----
  const float* bvec = bias + (size_t)e * Nsize;
  if constexpr (EPI == 0) {
    // stage bf16 tile in LDS ([128][128] ushort = exactly 32KB), coalesced out
    __syncthreads();
#pragma unroll
    for (int ni = 0; ni < 4; ++ni) {
      const int lc = wc * 64 + ni * 16 + r16;
      const float bv = bvec[n0 + lc];
#pragma unroll
      for (int mi = 0; mi < 4; ++mi) {
        const int lr0 = wr * 64 + mi * 16 + 4 * g4;
#pragma unroll
        for (int reg = 0; reg < 4; ++reg) {
          float v = acc[mi][ni][reg] + bv;
          v = 0.5f * v * (1.0f + erff(v * 0.70710678118654752f));
          lds[(lr0 + reg) * 128 + lc] = f2bf(v);
        }
      }
    }
    __syncthreads();
    unsigned short* C = (unsigned short*)Cout0 + (size_t)e * CAP * ldc;
#pragma unroll
    for (int it = 0; it < 8; ++it) {               // 2048 chunks of 8 shorts
      const int chunk = it * 256 + tid;            // r8 BUG was 16 iters (OOB)
      const int row = chunk >> 4, c8 = chunk & 15;
      *(float4*)(C + (size_t)(m0 + row) * ldc + n0 + c8 * 8) = *(const float4*)&lds[chunk * 8];
    }
  } else {
    float* C = (float*)(ks ? Cout1 : Cout0) + (size_t)e * CAP * ldc;
#pragma unroll
    for (int ni = 0; ni < 4; ++ni) {
      const int gc = n0 + wc * 64 + ni * 16 + r16;
#pragma unroll
      for (int mi = 0; mi < 4; ++mi) {
        const int gr0 = m0 + wr * 64 + mi * 16 + 4 * g4;
#pragma unroll
        for (int reg = 0; reg < 4; ++reg)
          C[(size_t)(gr0 + reg) * ldc + gc] = acc[mi][ni][reg];
      }
    }
  }
}

// ---------------- 6. Combine: out[t] = sum over kept slots w*(Y0+Y1+b2[e]) ----------------
__global__ __launch_bounds__(192)
void moe_combine(const float* __restrict__ Y0, const float* __restrict__ Y1,
                 const float* __restrict__ b2, const int* __restrict__ eidx,
                 const float* __restrict__ pw, const int* __restrict__ slotpos,
                 float* __restrict__ out)
{
  const int t = blockIdx.x;
  const int tid = threadIdx.x;
  float4 acc; acc.x = acc.y = acc.z = acc.w = 0.f;
#pragma unroll
  for (int s = 0; s < 2; ++s) {
    const int pos = slotpos[t * 2 + s];
    if (pos >= 0) {
      const int e = eidx[t * 2 + s];
      const float w = pw[t * 2 + s];
      const size_t ro = ((size_t)e * CAP + pos) * DMODEL;
      float4 y0 = ((const float4*)(Y0 + ro))[tid];
      float4 y1 = ((const float4*)(Y1 + ro))[tid];
      float4 bv = ((const float4*)(b2 + (size_t)e * DMODEL))[tid];
      acc.x += w * (y0.x + y1.x + bv.x);
      acc.y += w * (y0.y + y1.y + bv.y);
      acc.z += w * (y0.z + y1.z + bv.z);
      acc.w += w * (y0.w + y1.w + bv.w);
    }
  }
  ((float4*)out)[(size_t)t * (DMODEL / 4) + tid] = acc;
}

// ---------------- launch ----------------
extern "C" void kernel_launch(void* const* d_in, const int* in_sizes, int n_in,
                              void* d_out, int out_size, void* d_ws, size_t ws_size,
                              hipStream_t stream)
{
  const float* x  = (const float*)d_in[0];
  const float* Wr = (const float*)d_in[1];
  const float* w1 = (const float*)d_in[2];
  const float* b1 = (const float*)d_in[3];
  const float* w2 = (const float*)d_in[4];
  const float* b2 = (const float*)d_in[5];
  float* out = (float*)d_out;

  char* ws = (char*)d_ws;
  const size_t SZ_W1T = (size_t)NEXP * HDIM * DMODEL * 2;   // 37.75 MB
  const size_t SZ_W2T = (size_t)NEXP * DMODEL * HDIM * 2;   // 37.75 MB
  const size_t SZ_XG  = (size_t)NEXP * CAP * DMODEL * 2;    // 18.87 MB
  const size_t SZ_H   = (size_t)NEXP * CAP * HDIM * 2;      // 75.50 MB
  const size_t SZ_Y   = (size_t)NEXP * CAP * DMODEL * 4;    // 37.75 MB
  unsigned short* w1t = (unsigned short*)(ws);               size_t off = SZ_W1T;
  unsigned short* w2t = (unsigned short*)(ws + off);         off += SZ_W2T;
  unsigned short* Xg  = (unsigned short*)(ws + off);         off += SZ_XG;
  unsigned short* Hb  = (unsigned short*)(ws + off);         off += SZ_H;
  float*          Y0  = (float*)(ws + off);                  off += SZ_Y;
  int*   eidx    = (int*)(ws + off);                         off += (size_t)TOK * 2 * 4;
  float* pw      = (float*)(ws + off);                       off += (size_t)TOK * 2 * 4;
  int*   slotpos = (int*)(ws + off);                         off += (size_t)NFLAT * 4;
  int*   elist   = (int*)(ws + off);                         off += (size_t)NEXP * CAP * 4;
  int*   counts  = (int*)(ws + off);
  float* Y1 = (float*)w1t;   // alias: w1t dead after GEMM1; sizes match exactly

  // 1. router (fp64 logits -> exact top-2 ordering)
  moe_router<<<TOK / 4, 256, 0, stream>>>(x, Wr, eidx, pw);
  // 2. capacity assignment
  moe_assign<<<NEXP, 256, 0, stream>>>(eidx, slotpos, elist, counts);
  // 3. weight transposes (n-major bf16)
  transpose_bf16<<<dim3(HDIM / 64, DMODEL / 64, NEXP), 256, 0, stream>>>(w1, w1t, DMODEL, HDIM);
  transpose_bf16<<<dim3(DMODEL / 64, HDIM / 64, NEXP), 256, 0, stream>>>(w2, w2t, HDIM, DMODEL);
  // 4. gather per-expert token rows (bf16), zero pad rows
  moe_gather<<<dim3(CAP, NEXP), 64, 0, stream>>>(x, elist, counts, Xg);
  // 5. grouped GEMMs (reg-staged pipeline, 128x128, 3 blk/CU)
  //    GEMM1: [1536x3072x768]/expert -> 12*24*8 = 2304 blocks, NT=12
  moe_rs<0><<<2304, 256, 0, stream>>>(
      Xg, DMODEL, w1t, DMODEL, Hb, Hb, HDIM, b1, HDIM, /*NT=*/12, /*MT=*/12, /*NTN=*/24);
  //    GEMM2: [1536x768x3072]/expert, K-split x2 -> 12*6*2*8 = 1152 blocks, NT=24
  moe_rs<1><<<1152, 256, 0, stream>>>(
      Hb, HDIM, w2t, HDIM, Y0, Y1, DMODEL, b2, DMODEL, /*NT=*/24, /*MT=*/12, /*NTN=*/6);
  // 6. weighted combine (adds K-split partials + bias; deterministic)
  moe_combine<<<TOK, 192, 0, stream>>>(Y0, Y1, b2, eidx, pw, slotpos, out);
}

// Round 10
// 263.512 us; speedup vs baseline: 2.8224x; 2.8224x over previous
//
#include <hip/hip_runtime.h>
#include <hip/hip_bf16.h>
#include <math.h>

// Problem constants (B=4, S=2048, D=768, H=3072, E=8, K=2, cap_factor=1.5)
#define TOK    8192          // B*S tokens
#define DMODEL 768
#define HDIM   3072
#define NEXP   8
#define CAP    1536          // int((B*S/E)*1.5)
#define NFLAT  (TOK*2)

typedef __attribute__((ext_vector_type(8))) short bf16x8;
typedef __attribute__((ext_vector_type(4))) float f32x4;

static __device__ __forceinline__ unsigned short f2bf(float f) {
  unsigned int u = __float_as_uint(f);
  u += 0x7FFF + ((u >> 16) & 1);          // round-to-nearest-even
  return (unsigned short)(u >> 16);
}

// ---------------- 1. Router: fp64 logits, top-2, renormalized weights ----------------
__global__ __launch_bounds__(256)
void moe_router(const float* __restrict__ x, const float* __restrict__ Wr,
                int* __restrict__ eidx, float* __restrict__ pw)
{
  const int wid = threadIdx.x >> 6, lane = threadIdx.x & 63;
  const int t = blockIdx.x * 4 + wid;
  const float* xr = x + (size_t)t * DMODEL;
  double acc[NEXP];
#pragma unroll
  for (int e = 0; e < NEXP; ++e) acc[e] = 0.0;
  for (int j = 0; j < DMODEL / 64; ++j) {
    const int d = j * 64 + lane;
    const double xv = (double)xr[d];
    const float* wrow = Wr + (size_t)d * NEXP;
#pragma unroll
    for (int e = 0; e < NEXP; ++e) acc[e] += xv * (double)wrow[e];
  }
#pragma unroll
  for (int off = 32; off > 0; off >>= 1) {
#pragma unroll
    for (int e = 0; e < NEXP; ++e) acc[e] += __shfl_xor(acc[e], off, 64);
  }
  if (lane == 0) {
    int e0 = 0;
    for (int e = 1; e < NEXP; ++e) if (acc[e] > acc[e0]) e0 = e;
    int e1 = (e0 == 0) ? 1 : 0;
    for (int e = 0; e < NEXP; ++e) { if (e == e0) continue; if (acc[e] > acc[e1]) e1 = e; }
    const double p0 = 1.0 / (1.0 + exp(acc[e1] - acc[e0]));
    eidx[t * 2 + 0] = e0; eidx[t * 2 + 1] = e1;
    pw[t * 2 + 0] = (float)p0; pw[t * 2 + 1] = (float)(1.0 - p0);
  }
}

// ---------------- 2. Capacity assignment ----------------
__global__ __launch_bounds__(256)
void moe_assign(const int* __restrict__ eidx, int* __restrict__ slotpos,
                int* __restrict__ elist, int* __restrict__ counts)
{
  const int e = blockIdx.x;
  const int tid = threadIdx.x;
  const int base = tid * 64;
  int cnt = 0;
  for (int j = 0; j < 64; ++j) cnt += (eidx[base + j] == e);
  const int lane = tid & 63, wid = tid >> 6;
  int incl = cnt;
  for (int off = 1; off < 64; off <<= 1) {
    int u = __shfl_up(incl, off, 64);
    if (lane >= off) incl += u;
  }
  __shared__ int wsum[4];
  if (lane == 63) wsum[wid] = incl;
  __syncthreads();
  int wbase = 0;
  for (int w = 0; w < wid; ++w) wbase += wsum[w];
  int run = wbase + incl - cnt;
  for (int j = 0; j < 64; ++j) {
    const int n = base + j;
    if (eidx[n] == e) {
      const int pos = run++;
      slotpos[n] = (pos < CAP) ? pos : -1;
      if (pos < CAP) elist[e * CAP + pos] = n >> 1;
    }
  }
  if (tid == 255) {
    int tot = wbase + incl;
    counts[e] = (tot < CAP) ? tot : CAP;
  }
}

// ---------------- 3. Transpose + fp32->bf16 convert (weights) ----------------
__global__ __launch_bounds__(256)
void transpose_bf16(const float* __restrict__ in, unsigned short* __restrict__ out,
                    int R, int C)
{
  __shared__ unsigned short tile[64][65];
  const int e = blockIdx.z;
  in  += (size_t)e * R * C;
  out += (size_t)e * C * R;
  const int c0 = blockIdx.x * 64;
  const int r0 = blockIdx.y * 64;
  const int tid = threadIdx.x;
#pragma unroll
  for (int i = 0; i < 16; ++i) {
    const int L = tid + i * 256;
    const int r = L >> 6, c = L & 63;
    tile[r][c] = f2bf(in[(size_t)(r0 + r) * C + c0 + c]);
  }
  __syncthreads();
#pragma unroll
  for (int i = 0; i < 16; ++i) {
    const int L = tid + i * 256;
    const int rr = L & 63, cc = L >> 6;
    out[(size_t)(c0 + cc) * R + r0 + rr] = tile[rr][cc];
  }
}

// ---------------- 4. Gather tokens per expert into contiguous bf16 rows ----------------
__global__ __launch_bounds__(64)
void moe_gather(const float* __restrict__ x, const int* __restrict__ elist,
                const int* __restrict__ counts, unsigned short* __restrict__ Xg)
{
  const int p = blockIdx.x, e = blockIdx.y;
  const int lane = threadIdx.x;
  unsigned short* dst = Xg + ((size_t)e * CAP + p) * DMODEL;
  if (p >= counts[e]) {
    ushort4 z; z.x = z.y = z.z = z.w = 0;
#pragma unroll
    for (int j = 0; j < 3; ++j) ((ushort4*)dst)[j * 64 + lane] = z;
    return;
  }
  const int tok = elist[e * CAP + p];
  const float4* src = (const float4*)(x + (size_t)tok * DMODEL);
#pragma unroll
  for (int j = 0; j < 3; ++j) {
    float4 v = src[j * 64 + lane];
    ushort4 o;
    o.x = f2bf(v.x); o.y = f2bf(v.y); o.z = f2bf(v.z); o.w = f2bf(v.w);
    ((ushort4*)dst)[j * 64 + lane] = o;
  }
}

// ---------------- 5. Grouped GEMM: reg-staged, XOR-swizzled row-major LDS ----------------
// 128x128 tile, 256 thr = 4 waves (2x2), wave out 64x64, acc[4][4] (-> AGPRs).
// __launch_bounds__(256) with NO min-waves floor: r9 proved a min-waves hint
// makes the allocator cap arch-VGPRs at 64 and spill the staging regs
// (VGPR_Count=64, WRITE_SIZE 588MB vs 78MB output, VALUBusy 2.4%). Bare bound
// historically allocates ~88-128 with zero spill (r1/r4/r5).
// Transport: global_load_dwordx4 -> regs -> ds_write_b128; loads for tile t+1
// issue BEFORE compute(t) so HBM/L2 latency hides under MFMA (no gld_lds:
// its vmcnt(0)-in-barrier drain + 16x64B scattered segments are the common
// component of all 148-172us variants; row-contiguous source = 8x128B segs).
// LDS: [128][64] shorts, 16B-chunk XOR swizzle chunk^=(row&7) on BOTH write
// and read. Per-quarter-wave bank audit: write = 8 rows x 8 distinct chunks
// (2 lanes/bank-quad = free, m136); read = 16 rows, chunk=(kh*4+g4)^(row&7)
// -> 8 distinct bank-quads x 2 = free. (r8's post-mortem mislabeled this
// 8-way; the real r8 bug was the 16-iter OOB epilogue, fixed here: 8 iters.)
// EPI=0: bf16(gelu(acc+bias)) via LDS-staged coalesced 16B stores.
// EPI=1: direct f32 (clean, r5), bias folded into combine; ks picks Cout0/1.
template <int EPI>
__global__ __launch_bounds__(256)
void moe_rs(const unsigned short* __restrict__ Ag, int lda,
            const unsigned short* __restrict__ Bg, int ldb,
            void* __restrict__ Cout0, void* __restrict__ Cout1, int ldc,
            const float* __restrict__ bias,
            int Nsize, int NT, int MT, int NTN)
{
  __shared__ __align__(16) unsigned short lds[2 * 8192];   // A | B, 32 KiB
  unsigned short* const ldsA = lds;
  unsigned short* const ldsB = lds + 8192;

  // XCD swizzle: per-XCD contiguous chunk = one expert's tiles; mt fastest
  const int cpx = gridDim.x >> 3;
  const int swz = (blockIdx.x & 7) * cpx + (blockIdx.x >> 3);
  const int e  = swz / cpx;
  int rd = swz - e * cpx;
  const int mt = rd % MT;  rd /= MT;
  const int nt = rd % NTN;
  const int ks = rd / NTN;                   // K-split slice (0 unless GEMM2)
  const int m0 = mt * 128, n0 = nt * 128;
  const int kb = ks * NT * 64;

  const unsigned short* Ae = Ag + (size_t)e * CAP * lda;
  const unsigned short* Be = Bg + (size_t)e * Nsize * ldb;

  const int tid = threadIdx.x, lane = tid & 63, wid = tid >> 6;
  const int wr = wid >> 1, wc = wid & 1;
  const int r16 = lane & 15, g4 = lane >> 4;

  // staging addresses: thread covers rows srow+{0,32,64,96}, 16B chunk scol;
  // global source row-contiguous (8 lanes x 16B = 128B per row), LDS dest
  // chunk XOR-swizzled.
  const int srow  = tid >> 3;                 // 0..31
  const int scol  = tid & 7;                  // 0..7
  const int scolX = scol ^ (srow & 7);        // (srow+32k)&7 == srow&7
  const unsigned short* pA = Ae + (size_t)(m0 + srow) * lda + scol * 8 + kb;
  const unsigned short* pB = Be + (size_t)(n0 + srow) * ldb + scol * 8 + kb;
  unsigned short* qA = &ldsA[srow * 64 + scolX * 8];
  unsigned short* qB = &ldsB[srow * 64 + scolX * 8];

  float4 a0, a1, a2, a3, b0, b1, b2, b3;

#define LOADT(tt) do {                                                        \
    const size_t ko = (size_t)(tt) * 64;                                      \
    a0 = *(const float4*)(pA + ko);                                           \
    a1 = *(const float4*)(pA + ko + (size_t)32 * lda);                        \
    a2 = *(const float4*)(pA + ko + (size_t)64 * lda);                        \
    a3 = *(const float4*)(pA + ko + (size_t)96 * lda);                        \
    b0 = *(const float4*)(pB + ko);                                           \
    b1 = *(const float4*)(pB + ko + (size_t)32 * ldb);                        \
    b2 = *(const float4*)(pB + ko + (size_t)64 * ldb);                        \
    b3 = *(const float4*)(pB + ko + (size_t)96 * ldb);                        \
  } while (0)

#define STORET() do {                                                         \
    *(float4*)(qA)        = a0;  *(float4*)(qA + 2048) = a1;                  \
    *(float4*)(qA + 4096) = a2;  *(float4*)(qA + 6144) = a3;                  \
    *(float4*)(qB)        = b0;  *(float4*)(qB + 2048) = b1;                  \
    *(float4*)(qB + 4096) = b2;  *(float4*)(qB + 6144) = b3;                  \
  } while (0)

  f32x4 acc[4][4];
#pragma unroll
  for (int i = 0; i < 4; ++i)
#pragma unroll
    for (int j = 0; j < 4; ++j) acc[i][j] = (f32x4){0.f, 0.f, 0.f, 0.f};

  // per-thread read offsets (swizzled): chunk = (kh*4+g4) ^ (row&7); row&7==r16&7
  const int cx0 = (g4 ^ (r16 & 7)) * 8;
  const int rA = (wr * 64 + r16) * 64;    // + mi*16*64
  const int rB = (wc * 64 + r16) * 64;

  LOADT(0);
  for (int t = 0; t < NT; ++t) {
    __syncthreads();                 // all waves done reading LDS(t-1)
    STORET();                        // compiler inserts vmcnt wait here
    if (t + 1 < NT) LOADT(t + 1);    // in flight during compute(t)
    __syncthreads();                 // LDS(t) visible
#pragma unroll
    for (int kh = 0; kh < 2; ++kh) {
      const int cx = cx0 ^ (kh * 32);
      bf16x8 aF[4], bF[4];
#pragma unroll
      for (int mi = 0; mi < 4; ++mi)
        aF[mi] = *(const bf16x8*)&ldsA[rA + mi * 1024 + cx];
#pragma unroll
      for (int ni = 0; ni < 4; ++ni)
        bF[ni] = *(const bf16x8*)&ldsB[rB + ni * 1024 + cx];
#pragma unroll
      for (int mi = 0; mi < 4; ++mi)
#pragma unroll
        for (int ni = 0; ni < 4; ++ni)
          acc[mi][ni] = __builtin_amdgcn_mfma_f32_16x16x32_bf16(aF[mi], bF[ni], acc[mi][ni], 0, 0, 0);
    }
  }
#undef LOADT
#undef STORET

  // ---- epilogue. C/D layout: col = lane&15, row = 4*(lane>>4)+reg ----
  const float* bvec = bias + (size_t)e * Nsize;
  if constexpr (EPI == 0) {
    // stage bf16 tile in LDS ([128][128] ushort = exactly 32KB), coalesced out
    __syncthreads();
#pragma unroll
    for (int ni = 0; ni < 4; ++ni) {
      const int lc = wc * 64 + ni * 16 + r16;
      const float bv = bvec[n0 + lc];
#pragma unroll
      for (int mi = 0; mi < 4; ++mi) {
        const int lr0 = wr * 64 + mi * 16 + 4 * g4;
#pragma unroll
        for (int reg = 0; reg < 4; ++reg) {
          float v = acc[mi][ni][reg] + bv;
          v = 0.5f * v * (1.0f + erff(v * 0.70710678118654752f));
          lds[(lr0 + reg) * 128 + lc] = f2bf(v);
        }
      }
    }
    __syncthreads();
    unsigned short* C = (unsigned short*)Cout0 + (size_t)e * CAP * ldc;
#pragma unroll
    for (int it = 0; it < 8; ++it) {               // 2048 chunks of 8 shorts
      const int chunk = it * 256 + tid;            // (r8 bug: 16 iters = OOB)
      const int row = chunk >> 4, c8 = chunk & 15;
      *(float4*)(C + (size_t)(m0 + row) * ldc + n0 + c8 * 8) = *(const float4*)&lds[chunk * 8];
    }
  } else {
    float* C = (float*)(ks ? Cout1 : Cout0) + (size_t)e * CAP * ldc;
#pragma unroll
    for (int ni = 0; ni < 4; ++ni) {
      const int gc = n0 + wc * 64 + ni * 16 + r16;
#pragma unroll
      for (int mi = 0; mi < 4; ++mi) {
        const int gr0 = m0 + wr * 64 + mi * 16 + 4 * g4;
#pragma unroll
        for (int reg = 0; reg < 4; ++reg)
          C[(size_t)(gr0 + reg) * ldc + gc] = acc[mi][ni][reg];
      }
    }
  }
}

// ---------------- 6. Combine: out[t] = sum over kept slots w*(Y0+Y1+b2[e]) ----------------
__global__ __launch_bounds__(192)
void moe_combine(const float* __restrict__ Y0, const float* __restrict__ Y1,
                 const float* __restrict__ b2, const int* __restrict__ eidx,
                 const float* __restrict__ pw, const int* __restrict__ slotpos,
                 float* __restrict__ out)
{
  const int t = blockIdx.x;
  const int tid = threadIdx.x;
  float4 acc; acc.x = acc.y = acc.z = acc.w = 0.f;
#pragma unroll
  for (int s = 0; s < 2; ++s) {
    const int pos = slotpos[t * 2 + s];
    if (pos >= 0) {
      const int e = eidx[t * 2 + s];
      const float w = pw[t * 2 + s];
      const size_t ro = ((size_t)e * CAP + pos) * DMODEL;
      float4 y0 = ((const float4*)(Y0 + ro))[tid];
      float4 y1 = ((const float4*)(Y1 + ro))[tid];
      float4 bv = ((const float4*)(b2 + (size_t)e * DMODEL))[tid];
      acc.x += w * (y0.x + y1.x + bv.x);
      acc.y += w * (y0.y + y1.y + bv.y);
      acc.z += w * (y0.z + y1.z + bv.z);
      acc.w += w * (y0.w + y1.w + bv.w);
    }
  }
  ((float4*)out)[(size_t)t * (DMODEL / 4) + tid] = acc;
}

// ---------------- launch ----------------
extern "C" void kernel_launch(void* const* d_in, const int* in_sizes, int n_in,
                              void* d_out, int out_size, void* d_ws, size_t ws_size,
                              hipStream_t stream)
{
  const float* x  = (const float*)d_in[0];
  const float* Wr = (const float*)d_in[1];
  const float* w1 = (const float*)d_in[2];
  const float* b1 = (const float*)d_in[3];
  const float* w2 = (const float*)d_in[4];
  const float* b2 = (const float*)d_in[5];
  float* out = (float*)d_out;

  char* ws = (char*)d_ws;
  const size_t SZ_W1T = (size_t)NEXP * HDIM * DMODEL * 2;   // 37.75 MB
  const size_t SZ_W2T = (size_t)NEXP * DMODEL * HDIM * 2;   // 37.75 MB
  const size_t SZ_XG  = (size_t)NEXP * CAP * DMODEL * 2;    // 18.87 MB
  const size_t SZ_H   = (size_t)NEXP * CAP * HDIM * 2;      // 75.50 MB
  const size_t SZ_Y   = (size_t)NEXP * CAP * DMODEL * 4;    // 37.75 MB
  unsigned short* w1t = (unsigned short*)(ws);               size_t off = SZ_W1T;
  unsigned short* w2t = (unsigned short*)(ws + off);         off += SZ_W2T;
  unsigned short* Xg  = (unsigned short*)(ws + off);         off += SZ_XG;
  unsigned short* Hb  = (unsigned short*)(ws + off);         off += SZ_H;
  float*          Y0  = (float*)(ws + off);                  off += SZ_Y;
  int*   eidx    = (int*)(ws + off);                         off += (size_t)TOK * 2 * 4;
  float* pw      = (float*)(ws + off);                       off += (size_t)TOK * 2 * 4;
  int*   slotpos = (int*)(ws + off);                         off += (size_t)NFLAT * 4;
  int*   elist   = (int*)(ws + off);                         off += (size_t)NEXP * CAP * 4;
  int*   counts  = (int*)(ws + off);
  float* Y1 = (float*)w1t;   // alias: w1t dead after GEMM1; sizes match exactly

  // 1. router (fp64 logits -> exact top-2 ordering)
  moe_router<<<TOK / 4, 256, 0, stream>>>(x, Wr, eidx, pw);
  // 2. capacity assignment
  moe_assign<<<NEXP, 256, 0, stream>>>(eidx, slotpos, elist, counts);
  // 3. weight transposes (n-major bf16)
  transpose_bf16<<<dim3(HDIM / 64, DMODEL / 64, NEXP), 256, 0, stream>>>(w1, w1t, DMODEL, HDIM);
  transpose_bf16<<<dim3(DMODEL / 64, HDIM / 64, NEXP), 256, 0, stream>>>(w2, w2t, HDIM, DMODEL);
  // 4. gather per-expert token rows (bf16), zero pad rows
  moe_gather<<<dim3(CAP, NEXP), 64, 0, stream>>>(x, elist, counts, Xg);
  // 5. grouped GEMMs (reg-staged pipeline, 128x128)
  //    GEMM1: [1536x3072x768]/expert -> 12*24*8 = 2304 blocks, NT=12
  moe_rs<0><<<2304, 256, 0, stream>>>(
      Xg, DMODEL, w1t, DMODEL, Hb, Hb, HDIM, b1, HDIM, /*NT=*/12, /*MT=*/12, /*NTN=*/24);
  //    GEMM2: [1536x768x3072]/expert, K-split x2 -> 12*6*2*8 = 1152 blocks, NT=24
  moe_rs<1><<<1152, 256, 0, stream>>>(
      Hb, HDIM, w2t, HDIM, Y0, Y1, DMODEL, b2, DMODEL, /*NT=*/24, /*MT=*/12, /*NTN=*/6);
  // 6. weighted combine (adds K-split partials + bias; deterministic)
  moe_combine<<<TOK, 192, 0, stream>>>(Y0, Y1, b2, eidx, pw, slotpos, out);
}

// Round 11
// 244.749 us; speedup vs baseline: 3.0388x; 1.0767x over previous
//
#include <hip/hip_runtime.h>
#include <hip/hip_bf16.h>
#include <math.h>

// Problem constants (B=4, S=2048, D=768, H=3072, E=8, K=2, cap_factor=1.5)
#define TOK    8192          // B*S tokens
#define DMODEL 768
#define HDIM   3072
#define NEXP   8
#define CAP    1536          // int((B*S/E)*1.5)
#define NFLAT  (TOK*2)

typedef __attribute__((ext_vector_type(8))) short bf16x8;
typedef __attribute__((ext_vector_type(4))) float f32x4;

static __device__ __forceinline__ unsigned short f2bf(float f) {
  unsigned int u = __float_as_uint(f);
  u += 0x7FFF + ((u >> 16) & 1);          // round-to-nearest-even
  return (unsigned short)(u >> 16);
}

// fast gelu: v*sigmoid(2y), y = 0.79788456*(v + 0.044715 v^3); ~8 VALU vs ~22 for erff.
// max |delta vs exact-erf gelu| ~1e-3 < bf16 rounding quantum of hidden (~8e-3).
static __device__ __forceinline__ float fast_gelu(float v) {
  const float v2 = v * v;
  const float y2 = v * (1.59576912f + 0.07135534f * v2);   // 2*y
  const float e  = __expf(y2);
  return v - v * __builtin_amdgcn_rcpf(e + 1.0f);
}

// ---------------- 1. Router: fp64 logits, top-2, renormalized weights ----------------
__global__ __launch_bounds__(256)
void moe_router(const float* __restrict__ x, const float* __restrict__ Wr,
                int* __restrict__ eidx, float* __restrict__ pw)
{
  const int wid = threadIdx.x >> 6, lane = threadIdx.x & 63;
  const int t = blockIdx.x * 4 + wid;
  const float* xr = x + (size_t)t * DMODEL;
  double acc[NEXP];
#pragma unroll
  for (int e = 0; e < NEXP; ++e) acc[e] = 0.0;
  for (int j = 0; j < DMODEL / 64; ++j) {
    const int d = j * 64 + lane;
    const double xv = (double)xr[d];
    const float* wrow = Wr + (size_t)d * NEXP;
#pragma unroll
    for (int e = 0; e < NEXP; ++e) acc[e] += xv * (double)wrow[e];
  }
#pragma unroll
  for (int off = 32; off > 0; off >>= 1) {
#pragma unroll
    for (int e = 0; e < NEXP; ++e) acc[e] += __shfl_xor(acc[e], off, 64);
  }
  if (lane == 0) {
    int e0 = 0;
    for (int e = 1; e < NEXP; ++e) if (acc[e] > acc[e0]) e0 = e;
    int e1 = (e0 == 0) ? 1 : 0;
    for (int e = 0; e < NEXP; ++e) { if (e == e0) continue; if (acc[e] > acc[e1]) e1 = e; }
    const double p0 = 1.0 / (1.0 + exp(acc[e1] - acc[e0]));
    eidx[t * 2 + 0] = e0; eidx[t * 2 + 1] = e1;
    pw[t * 2 + 0] = (float)p0; pw[t * 2 + 1] = (float)(1.0 - p0);
  }
}

// ---------------- 2. Capacity assignment ----------------
__global__ __launch_bounds__(256)
void moe_assign(const int* __restrict__ eidx, int* __restrict__ slotpos,
                int* __restrict__ elist, int* __restrict__ counts)
{
  const int e = blockIdx.x;
  const int tid = threadIdx.x;
  const int base = tid * 64;
  int cnt = 0;
  for (int j = 0; j < 64; ++j) cnt += (eidx[base + j] == e);
  const int lane = tid & 63, wid = tid >> 6;
  int incl = cnt;
  for (int off = 1; off < 64; off <<= 1) {
    int u = __shfl_up(incl, off, 64);
    if (lane >= off) incl += u;
  }
  __shared__ int wsum[4];
  if (lane == 63) wsum[wid] = incl;
  __syncthreads();
  int wbase = 0;
  for (int w = 0; w < wid; ++w) wbase += wsum[w];
  int run = wbase + incl - cnt;
  for (int j = 0; j < 64; ++j) {
    const int n = base + j;
    if (eidx[n] == e) {
      const int pos = run++;
      slotpos[n] = (pos < CAP) ? pos : -1;
      if (pos < CAP) elist[e * CAP + pos] = n >> 1;
    }
  }
  if (tid == 255) {
    int tot = wbase + incl;
    counts[e] = (tot < CAP) ? tot : CAP;
  }
}

// ---------------- 3. Transpose + fp32->bf16 convert (weights) ----------------
__global__ __launch_bounds__(256)
void transpose_bf16(const float* __restrict__ in, unsigned short* __restrict__ out,
                    int R, int C)
{
  __shared__ unsigned short tile[64][65];
  const int e = blockIdx.z;
  in  += (size_t)e * R * C;
  out += (size_t)e * C * R;
  const int c0 = blockIdx.x * 64;
  const int r0 = blockIdx.y * 64;
  const int tid = threadIdx.x;
#pragma unroll
  for (int i = 0; i < 16; ++i) {
    const int L = tid + i * 256;
    const int r = L >> 6, c = L & 63;
    tile[r][c] = f2bf(in[(size_t)(r0 + r) * C + c0 + c]);
  }
  __syncthreads();
#pragma unroll
  for (int i = 0; i < 16; ++i) {
    const int L = tid + i * 256;
    const int rr = L & 63, cc = L >> 6;
    out[(size_t)(c0 + cc) * R + r0 + rr] = tile[rr][cc];
  }
}

// ---------------- 4. Gather tokens per expert into contiguous bf16 rows ----------------
__global__ __launch_bounds__(64)
void moe_gather(const float* __restrict__ x, const int* __restrict__ elist,
                const int* __restrict__ counts, unsigned short* __restrict__ Xg)
{
  const int p = blockIdx.x, e = blockIdx.y;
  const int lane = threadIdx.x;
  unsigned short* dst = Xg + ((size_t)e * CAP + p) * DMODEL;
  if (p >= counts[e]) {
    ushort4 z; z.x = z.y = z.z = z.w = 0;
#pragma unroll
    for (int j = 0; j < 3; ++j) ((ushort4*)dst)[j * 64 + lane] = z;
    return;
  }
  const int tok = elist[e * CAP + p];
  const float4* src = (const float4*)(x + (size_t)tok * DMODEL);
#pragma unroll
  for (int j = 0; j < 3; ++j) {
    float4 v = src[j * 64 + lane];
    ushort4 o;
    o.x = f2bf(v.x); o.y = f2bf(v.y); o.z = f2bf(v.z); o.w = f2bf(v.w);
    ((ushort4*)dst)[j * 64 + lane] = o;
  }
}

// ---------------- 5. Grouped GEMM: reg-staged, XOR-swizzled row-major LDS ----------------
// (r10-verified: 98us/GEMM, VGPR 76, no spill, clean WRITE_SIZE.)
// 128x128 tile, 256 thr = 4 waves (2x2), wave out 64x64, acc[4][4] (-> AGPRs).
// Bare __launch_bounds__(256): a min-waves floor makes the allocator cap arch
// VGPRs at 64 and spill the staging regs (r9: 588MB scratch writes).
// Transport: global_load_dwordx4 -> regs -> ds_write_b128; loads for tile t+1
// issue BEFORE compute(t). LDS [128][64] shorts, 16B-chunk XOR swizzle on both
// write and read (2-way aliasing = free, m136).
// ORD=0: mt fastest (GEMM1: B-slice hot, A panel 2.36MB becomes L2-resident).
// ORD=1: nt fastest (GEMM2: A-slice 393KB hot, B K-half 2.25MB L2-resident;
//        r10's mt-fastest re-streamed the 4.7MB A K-half -> ~450MB fetch).
// EPI=0: bf16(fast_gelu(acc+bias)) via LDS-staged coalesced 16B stores.
//        (r10: exact erff = ~1280 VALU instr/wave = ~2/3 of the 56% VALUBusy.)
// EPI=1: direct f32, bias folded into combine; ks picks Cout0/1.
template <int EPI, int ORD>
__global__ __launch_bounds__(256)
void moe_rs(const unsigned short* __restrict__ Ag, int lda,
            const unsigned short* __restrict__ Bg, int ldb,
            void* __restrict__ Cout0, void* __restrict__ Cout1, int ldc,
            const float* __restrict__ bias,
            int Nsize, int NT, int MT, int NTN)
{
  __shared__ __align__(16) unsigned short lds[2 * 8192];   // A | B, 32 KiB
  unsigned short* const ldsA = lds;
  unsigned short* const ldsB = lds + 8192;

  // XCD swizzle: per-XCD contiguous chunk = one expert's tiles
  const int cpx = gridDim.x >> 3;
  const int swz = (blockIdx.x & 7) * cpx + (blockIdx.x >> 3);
  const int e  = swz / cpx;
  int rd = swz - e * cpx;
  int mt, nt, ks;
  if (ORD == 0) { mt = rd % MT;  rd /= MT;  nt = rd % NTN; ks = rd / NTN; }
  else          { nt = rd % NTN; rd /= NTN; mt = rd % MT;  ks = rd / MT;  }
  const int m0 = mt * 128, n0 = nt * 128;
  const int kb = ks * NT * 64;

  const unsigned short* Ae = Ag + (size_t)e * CAP * lda;
  const unsigned short* Be = Bg + (size_t)e * Nsize * ldb;

  const int tid = threadIdx.x, lane = tid & 63, wid = tid >> 6;
  const int wr = wid >> 1, wc = wid & 1;
  const int r16 = lane & 15, g4 = lane >> 4;

  // staging: rows srow+{0,32,64,96}, 16B chunk scol; global row-contiguous
  // (8 lanes x 16B = 128B per row), LDS dest chunk XOR-swizzled.
  const int srow  = tid >> 3;                 // 0..31
  const int scol  = tid & 7;                  // 0..7
  const int scolX = scol ^ (srow & 7);        // (srow+32k)&7 == srow&7
  const unsigned short* pA = Ae + (size_t)(m0 + srow) * lda + scol * 8 + kb;
  const unsigned short* pB = Be + (size_t)(n0 + srow) * ldb + scol * 8 + kb;
  unsigned short* qA = &ldsA[srow * 64 + scolX * 8];
  unsigned short* qB = &ldsB[srow * 64 + scolX * 8];

  float4 a0, a1, a2, a3, b0, b1, b2, b3;

#define LOADT(tt) do {                                                        \
    const size_t ko = (size_t)(tt) * 64;                                      \
    a0 = *(const float4*)(pA + ko);                                           \
    a1 = *(const float4*)(pA + ko + (size_t)32 * lda);                        \
    a2 = *(const float4*)(pA + ko + (size_t)64 * lda);                        \
    a3 = *(const float4*)(pA + ko + (size_t)96 * lda);                        \
    b0 = *(const float4*)(pB + ko);                                           \
    b1 = *(const float4*)(pB + ko + (size_t)32 * ldb);                        \
    b2 = *(const float4*)(pB + ko + (size_t)64 * ldb);                        \
    b3 = *(const float4*)(pB + ko + (size_t)96 * ldb);                        \
  } while (0)

#define STORET() do {                                                         \
    *(float4*)(qA)        = a0;  *(float4*)(qA + 2048) = a1;                  \
    *(float4*)(qA + 4096) = a2;  *(float4*)(qA + 6144) = a3;                  \
    *(float4*)(qB)        = b0;  *(float4*)(qB + 2048) = b1;                  \
    *(float4*)(qB + 4096) = b2;  *(float4*)(qB + 6144) = b3;                  \
  } while (0)

  f32x4 acc[4][4];
#pragma unroll
  for (int i = 0; i < 4; ++i)
#pragma unroll
    for (int j = 0; j < 4; ++j) acc[i][j] = (f32x4){0.f, 0.f, 0.f, 0.f};

  // per-thread read offsets (swizzled): chunk = (kh*4+g4) ^ (row&7)
  const int cx0 = (g4 ^ (r16 & 7)) * 8;
  const int rA = (wr * 64 + r16) * 64;    // + mi*16*64
  const int rB = (wc * 64 + r16) * 64;

  LOADT(0);
  for (int t = 0; t < NT; ++t) {
    __syncthreads();                 // all waves done reading LDS(t-1)
    STORET();                        // compiler inserts vmcnt wait here
    if (t + 1 < NT) LOADT(t + 1);    // in flight during compute(t)
    __syncthreads();                 // LDS(t) visible
#pragma unroll
    for (int kh = 0; kh < 2; ++kh) {
      const int cx = cx0 ^ (kh * 32);
      bf16x8 aF[4], bF[4];
#pragma unroll
      for (int mi = 0; mi < 4; ++mi)
        aF[mi] = *(const bf16x8*)&ldsA[rA + mi * 1024 + cx];
#pragma unroll
      for (int ni = 0; ni < 4; ++ni)
        bF[ni] = *(const bf16x8*)&ldsB[rB + ni * 1024 + cx];
#pragma unroll
      for (int mi = 0; mi < 4; ++mi)
#pragma unroll
        for (int ni = 0; ni < 4; ++ni)
          acc[mi][ni] = __builtin_amdgcn_mfma_f32_16x16x32_bf16(aF[mi], bF[ni], acc[mi][ni], 0, 0, 0);
    }
  }
#undef LOADT
#undef STORET

  // ---- epilogue. C/D layout: col = lane&15, row = 4*(lane>>4)+reg ----
  const float* bvec = bias + (size_t)e * Nsize;
  if constexpr (EPI == 0) {
    // stage bf16 tile in LDS ([128][128] ushort = exactly 32KB), coalesced out
    __syncthreads();
#pragma unroll
    for (int ni = 0; ni < 4; ++ni) {
      const int lc = wc * 64 + ni * 16 + r16;
      const float bv = bvec[n0 + lc];
#pragma unroll
      for (int mi = 0; mi < 4; ++mi) {
        const int lr0 = wr * 64 + mi * 16 + 4 * g4;
#pragma unroll
        for (int reg = 0; reg < 4; ++reg) {
          lds[(lr0 + reg) * 128 + lc] = f2bf(fast_gelu(acc[mi][ni][reg] + bv));
        }
      }
    }
    __syncthreads();
    unsigned short* C = (unsigned short*)Cout0 + (size_t)e * CAP * ldc;
#pragma unroll
    for (int it = 0; it < 8; ++it) {               // 2048 chunks of 8 shorts
      const int chunk = it * 256 + tid;
      const int row = chunk >> 4, c8 = chunk & 15;
      *(float4*)(C + (size_t)(m0 + row) * ldc + n0 + c8 * 8) = *(const float4*)&lds[chunk * 8];
    }
  } else {
    float* C = (float*)(ks ? Cout1 : Cout0) + (size_t)e * CAP * ldc;
#pragma unroll
    for (int ni = 0; ni < 4; ++ni) {
      const int gc = n0 + wc * 64 + ni * 16 + r16;
#pragma unroll
      for (int mi = 0; mi < 4; ++mi) {
        const int gr0 = m0 + wr * 64 + mi * 16 + 4 * g4;
#pragma unroll
        for (int reg = 0; reg < 4; ++reg)
          C[(size_t)(gr0 + reg) * ldc + gc] = acc[mi][ni][reg];
      }
    }
  }
}

// ---------------- 6. Combine: out[t] = sum over kept slots w*(Y0+Y1+b2[e]) ----------------
__global__ __launch_bounds__(192)
void moe_combine(const float* __restrict__ Y0, const float* __restrict__ Y1,
                 const float* __restrict__ b2, const int* __restrict__ eidx,
                 const float* __restrict__ pw, const int* __restrict__ slotpos,
                 float* __restrict__ out)
{
  const int t = blockIdx.x;
  const int tid = threadIdx.x;
  float4 acc; acc.x = acc.y = acc.z = acc.w = 0.f;
#pragma unroll
  for (int s = 0; s < 2; ++s) {
    const int pos = slotpos[t * 2 + s];
    if (pos >= 0) {
      const int e = eidx[t * 2 + s];
      const float w = pw[t * 2 + s];
      const size_t ro = ((size_t)e * CAP + pos) * DMODEL;
      float4 y0 = ((const float4*)(Y0 + ro))[tid];
      float4 y1 = ((const float4*)(Y1 + ro))[tid];
      float4 bv = ((const float4*)(b2 + (size_t)e * DMODEL))[tid];
      acc.x += w * (y0.x + y1.x + bv.x);
      acc.y += w * (y0.y + y1.y + bv.y);
      acc.z += w * (y0.z + y1.z + bv.z);
      acc.w += w * (y0.w + y1.w + bv.w);
    }
  }
  ((float4*)out)[(size_t)t * (DMODEL / 4) + tid] = acc;
}

// ---------------- launch ----------------
extern "C" void kernel_launch(void* const* d_in, const int* in_sizes, int n_in,
                              void* d_out, int out_size, void* d_ws, size_t ws_size,
                              hipStream_t stream)
{
  const float* x  = (const float*)d_in[0];
  const float* Wr = (const float*)d_in[1];
  const float* w1 = (const float*)d_in[2];
  const float* b1 = (const float*)d_in[3];
  const float* w2 = (const float*)d_in[4];
  const float* b2 = (const float*)d_in[5];
  float* out = (float*)d_out;

  char* ws = (char*)d_ws;
  const size_t SZ_W1T = (size_t)NEXP * HDIM * DMODEL * 2;   // 37.75 MB
  const size_t SZ_W2T = (size_t)NEXP * DMODEL * HDIM * 2;   // 37.75 MB
  const size_t SZ_XG  = (size_t)NEXP * CAP * DMODEL * 2;    // 18.87 MB
  const size_t SZ_H   = (size_t)NEXP * CAP * HDIM * 2;      // 75.50 MB
  const size_t SZ_Y   = (size_t)NEXP * CAP * DMODEL * 4;    // 37.75 MB
  unsigned short* w1t = (unsigned short*)(ws);               size_t off = SZ_W1T;
  unsigned short* w2t = (unsigned short*)(ws + off);         off += SZ_W2T;
  unsigned short* Xg  = (unsigned short*)(ws + off);         off += SZ_XG;
  unsigned short* Hb  = (unsigned short*)(ws + off);         off += SZ_H;
  float*          Y0  = (float*)(ws + off);                  off += SZ_Y;
  int*   eidx    = (int*)(ws + off);                         off += (size_t)TOK * 2 * 4;
  float* pw      = (float*)(ws + off);                       off += (size_t)TOK * 2 * 4;
  int*   slotpos = (int*)(ws + off);                         off += (size_t)NFLAT * 4;
  int*   elist   = (int*)(ws + off);                         off += (size_t)NEXP * CAP * 4;
  int*   counts  = (int*)(ws + off);
  float* Y1 = (float*)w1t;   // alias: w1t dead after GEMM1; sizes match exactly

  // 1. router (fp64 logits -> exact top-2 ordering)
  moe_router<<<TOK / 4, 256, 0, stream>>>(x, Wr, eidx, pw);
  // 2. capacity assignment
  moe_assign<<<NEXP, 256, 0, stream>>>(eidx, slotpos, elist, counts);
  // 3. weight transposes (n-major bf16)
  transpose_bf16<<<dim3(HDIM / 64, DMODEL / 64, NEXP), 256, 0, stream>>>(w1, w1t, DMODEL, HDIM);
  transpose_bf16<<<dim3(DMODEL / 64, HDIM / 64, NEXP), 256, 0, stream>>>(w2, w2t, HDIM, DMODEL);
  // 4. gather per-expert token rows (bf16), zero pad rows
  moe_gather<<<dim3(CAP, NEXP), 64, 0, stream>>>(x, elist, counts, Xg);
  // 5. grouped GEMMs (reg-staged pipeline, 128x128)
  //    GEMM1: [1536x3072x768]/expert -> 12*24*8 = 2304 blocks, NT=12, mt-fastest
  moe_rs<0, 0><<<2304, 256, 0, stream>>>(
      Xg, DMODEL, w1t, DMODEL, Hb, Hb, HDIM, b1, HDIM, /*NT=*/12, /*MT=*/12, /*NTN=*/24);
  //    GEMM2: [1536x768x3072]/expert, K-split x2 -> 1152 blocks, NT=24, nt-fastest
  moe_rs<1, 1><<<1152, 256, 0, stream>>>(
      Hb, HDIM, w2t, HDIM, Y0, Y1, DMODEL, b2, DMODEL, /*NT=*/24, /*MT=*/12, /*NTN=*/6);
  // 6. weighted combine (adds K-split partials + bias; deterministic)
  moe_combine<<<TOK, 192, 0, stream>>>(Y0, Y1, b2, eidx, pw, slotpos, out);
}